// Round 1
// baseline (2846.337 us; speedup 1.0000x reference)
//
#include <hip/hip_runtime.h>
#include <math.h>

// Problem constants
#define N_IMG 128
#define IC 8
#define IH 128
#define IW 128
#define OC 64
#define OH 126
#define OW 126
#define NG 16
#define CPG 4          // channels per group
#define PH 31
#define PW 31
#define GN_EPS 1e-5f

// conv4: compute 4 consecutive output columns x 4 channels of the 3x3 conv.
// acc[j][ch] must be pre-initialized (bias). Weights in LDS laid out
// [ic][kh][kw][ch] (12 floats per (ic,kh), contiguous -> ds_read_b128 x3).
// If edge==true, columns ow+4..ow+5 are out of range and treated as 0
// (outputs j=2,3 are then garbage and must be masked by the caller).
__device__ __forceinline__ void conv4(const float* __restrict__ xb,
                                      const float* wlds_,
                                      int oh, int ow, bool edge,
                                      float acc[4][CPG]) {
    for (int ic = 0; ic < IC; ic++) {
        const float* xr = xb + ic * (IH * IW) + oh * IW + ow;
#pragma unroll
        for (int kh = 0; kh < 3; kh++) {
            const float* xrr = xr + kh * IW;
            float4 f4 = *(const float4*)xrr;           // cols ow..ow+3 (16B aligned)
            float v0 = f4.x, v1 = f4.y, v2 = f4.z, v3 = f4.w;
            float v4 = 0.f, v5 = 0.f;
            if (!edge) {
                float2 f2 = *(const float2*)(xrr + 4); // cols ow+4..ow+5
                v4 = f2.x; v5 = f2.y;
            }
            const float* wk = wlds_ + (ic * 3 + kh) * 12;
            float wr[12];
#pragma unroll
            for (int t = 0; t < 12; t++) wr[t] = wk[t];
#pragma unroll
            for (int ch = 0; ch < CPG; ch++) {
                float w0 = wr[0 * 4 + ch];
                float w1 = wr[1 * 4 + ch];
                float w2 = wr[2 * 4 + ch];
                acc[0][ch] = fmaf(v0, w0, fmaf(v1, w1, fmaf(v2, w2, acc[0][ch])));
                acc[1][ch] = fmaf(v1, w0, fmaf(v2, w1, fmaf(v3, w2, acc[1][ch])));
                acc[2][ch] = fmaf(v2, w0, fmaf(v3, w1, fmaf(v4, w2, acc[2][ch])));
                acc[3][ch] = fmaf(v3, w0, fmaf(v4, w1, fmaf(v5, w2, acc[3][ch])));
            }
        }
    }
}

__launch_bounds__(256)
__global__ void fused_conv_gn_pool_kernel(const float* __restrict__ x,
                                          const float* __restrict__ conv_w,
                                          const float* __restrict__ conv_b,
                                          const float* __restrict__ gn_w,
                                          const float* __restrict__ gn_b,
                                          const float* __restrict__ scale,
                                          float* __restrict__ out) {
    const int blk = blockIdx.x;     // 0..2047  == n*16 + g
    const int n = blk >> 4;
    const int g = blk & 15;
    const int tid = threadIdx.x;

    __shared__ float wlds[IC * 3 * 3 * CPG];   // 288 floats, [ic][kh][kw][ch]
    __shared__ float red[8];                    // 4 waves x {sum, sumsq}
    __shared__ float stats[2];                  // mean, rstd

    // Stage weights for this group's 4 channels into LDS, transposed to
    // [ic][kh][kw][ch] so the inner loop reads contiguous 16B chunks.
    for (int t = tid; t < IC * 3 * 3 * CPG; t += 256) {
        int ch = t & 3;
        int r = t >> 2;                        // ic*9 + kh*3 + kw
        wlds[t] = conv_w[(g * CPG + ch) * (IC * 9) + r];
    }
    float bias[CPG];
#pragma unroll
    for (int ch = 0; ch < CPG; ch++) bias[ch] = conv_b[g * CPG + ch];
    __syncthreads();

    const float* xb = x + (size_t)n * (IC * IH * IW);

    // ---------------- Phase 1: conv -> per-(n,g) sum / sumsq ----------------
    float s = 0.f, ss = 0.f;
    // 126 rows x 32 col-groups of 4 (last group has only 2 valid cols)
    for (int p = tid; p < OH * 32; p += 256) {
        int oh = p >> 5;
        int owq = p & 31;
        int ow = owq << 2;
        bool edge = (owq == 31);
        float acc[4][CPG];
#pragma unroll
        for (int j = 0; j < 4; j++)
#pragma unroll
            for (int ch = 0; ch < CPG; ch++) acc[j][ch] = bias[ch];

        conv4(xb, wlds, oh, ow, edge, acc);

        int jmax = edge ? 2 : 4;
#pragma unroll
        for (int j = 0; j < 4; j++) {
            if (j < jmax) {
#pragma unroll
                for (int ch = 0; ch < CPG; ch++) {
                    float v = acc[j][ch];
                    s += v;
                    ss = fmaf(v, v, ss);
                }
            }
        }
    }

    // Block reduction: wave shuffle then LDS across 4 waves.
#pragma unroll
    for (int off = 32; off > 0; off >>= 1) {
        s  += __shfl_down(s, off, 64);
        ss += __shfl_down(ss, off, 64);
    }
    int wave = tid >> 6;
    if ((tid & 63) == 0) { red[wave] = s; red[4 + wave] = ss; }
    __syncthreads();
    if (tid == 0) {
        float S  = red[0] + red[1] + red[2] + red[3];
        float SS = red[4] + red[5] + red[6] + red[7];
        const float inv_count = 1.f / (float)(CPG * OH * OW);
        float mean = S * inv_count;
        float var = SS * inv_count - mean * mean;
        if (var < 0.f) var = 0.f;
        stats[0] = mean;
        stats[1] = rsqrtf(var + GN_EPS);
    }
    __syncthreads();
    const float mean = stats[0];
    const float rstd = stats[1];

    // Fold GN affine + per-channel scale into y*a + b form.
    float aff_a[CPG], aff_b[CPG];
#pragma unroll
    for (int ch = 0; ch < CPG; ch++) {
        int c = g * CPG + ch;
        float gw = gn_w[c], sc = scale[c];
        aff_a[ch] = rstd * gw * sc;
        aff_b[ch] = (gn_b[c] - mean * rstd * gw) * sc;
    }

    // ---------------- Phase 2: conv (recompute) -> affine -> maxpool -> clamp
    for (int q = tid; q < PH * PW; q += 256) {
        int ph = q / PW;
        int pw = q - ph * PW;
        float m[CPG];
#pragma unroll
        for (int ch = 0; ch < CPG; ch++) m[ch] = -INFINITY;

        for (int r = 0; r < 4; r++) {
            int oh = 4 * ph + r;
            int ow = 4 * pw;
            float acc[4][CPG];
#pragma unroll
            for (int j = 0; j < 4; j++)
#pragma unroll
                for (int ch = 0; ch < CPG; ch++) acc[j][ch] = bias[ch];

            conv4(xb, wlds, oh, ow, false, acc);

#pragma unroll
            for (int j = 0; j < 4; j++)
#pragma unroll
                for (int ch = 0; ch < CPG; ch++) {
                    float v = fmaf(acc[j][ch], aff_a[ch], aff_b[ch]);
                    m[ch] = fmaxf(m[ch], v);
                }
        }
#pragma unroll
        for (int ch = 0; ch < CPG; ch++) {
            int c = g * CPG + ch;
            float v = m[ch];
            v = fminf(fmaxf(v, 0.f), 1.f);
            out[(((size_t)n * OC + c) * PH + ph) * PW + pw] = v;
        }
    }
}

extern "C" void kernel_launch(void* const* d_in, const int* in_sizes, int n_in,
                              void* d_out, int out_size, void* d_ws, size_t ws_size,
                              hipStream_t stream) {
    const float* x      = (const float*)d_in[0];
    const float* conv_w = (const float*)d_in[1];
    const float* conv_b = (const float*)d_in[2];
    const float* gn_w   = (const float*)d_in[3];
    const float* gn_b   = (const float*)d_in[4];
    const float* scale  = (const float*)d_in[5];
    float* out = (float*)d_out;

    dim3 grid(N_IMG * NG);   // one block per (n, group)
    dim3 block(256);
    hipLaunchKernelGGL(fused_conv_gn_pool_kernel, grid, block, 0, stream,
                       x, conv_w, conv_b, gn_w, gn_b, scale, out);
}

// Round 2
// 435.872 us; speedup vs baseline: 6.5302x; 6.5302x over previous
//
#include <hip/hip_runtime.h>
#include <math.h>

// Problem constants
#define N_IMG 128
#define IC 8
#define IH 128
#define IW 128
#define OC 64
#define OH 126
#define OW 126
#define NG 16
#define CPG 4          // channels per group
#define PH 31
#define PW 31
#define GN_EPS 1e-5f

// conv4: compute 4 consecutive output columns x 4 channels of the 3x3 conv.
// acc[j][ch] must be pre-initialized (bias). Weights in LDS laid out
// [ic][kh][kw][ch] (12 floats per (ic,kh) -> 3x ds_read_b128, broadcast).
// If edge==true, columns ow+4..ow+5 are not loaded (outputs j=2,3 garbage,
// caller must mask).
__device__ __forceinline__ void conv4(const float* __restrict__ xb,
                                      const float* wlds_,
                                      int oh, int ow, bool edge,
                                      float acc[4][CPG]) {
#pragma unroll 1
    for (int ic = 0; ic < IC; ic++) {
        const float* xr = xb + ic * (IH * IW) + oh * IW + ow;
#pragma unroll
        for (int kh = 0; kh < 3; kh++) {
            const float* xrr = xr + kh * IW;
            float4 f4 = *(const float4*)xrr;           // cols ow..ow+3 (16B aligned)
            float v0 = f4.x, v1 = f4.y, v2 = f4.z, v3 = f4.w;
            float v4 = 0.f, v5 = 0.f;
            if (!edge) {
                float2 f2 = *(const float2*)(xrr + 4); // cols ow+4..ow+5
                v4 = f2.x; v5 = f2.y;
            }
            const float* wk = wlds_ + (ic * 3 + kh) * 12;
            float wr[12];
#pragma unroll
            for (int t = 0; t < 12; t++) wr[t] = wk[t];
#pragma unroll
            for (int ch = 0; ch < CPG; ch++) {
                float w0 = wr[0 * 4 + ch];
                float w1 = wr[1 * 4 + ch];
                float w2 = wr[2 * 4 + ch];
                acc[0][ch] = fmaf(v0, w0, fmaf(v1, w1, fmaf(v2, w2, acc[0][ch])));
                acc[1][ch] = fmaf(v1, w0, fmaf(v2, w1, fmaf(v3, w2, acc[1][ch])));
                acc[2][ch] = fmaf(v2, w0, fmaf(v3, w1, fmaf(v4, w2, acc[2][ch])));
                acc[3][ch] = fmaf(v3, w0, fmaf(v4, w1, fmaf(v5, w2, acc[3][ch])));
            }
        }
    }
}

// One block per (n, group). Single conv pass:
//  - accumulate sum/sumsq for GroupNorm stats
//  - track per-pool-window running extreme M = max(v * sgn[ch]) in registers
//    (sign of the fused affine slope is known before stats since rstd > 0)
// Then out = clamp(rstd*|gn_w*scale|*M + (gn_b - mean*rstd*gn_w)*scale, 0, 1).
__launch_bounds__(256, 4)
__global__ void fused_conv_gn_pool_kernel(const float* __restrict__ x,
                                          const float* __restrict__ conv_w,
                                          const float* __restrict__ conv_b,
                                          const float* __restrict__ gn_w,
                                          const float* __restrict__ gn_b,
                                          const float* __restrict__ scale,
                                          float* __restrict__ out) {
    const int blk = blockIdx.x;     // 0..2047 == n*16 + g
    const int n = blk >> 4;
    const int g = blk & 15;
    const int tid = threadIdx.x;

    __shared__ float wlds[IC * 3 * 3 * CPG];   // 288 floats, [ic][kh][kw][ch]
    __shared__ float red[8];                    // 4 waves x {sum, sumsq}
    __shared__ float stats[2];                  // mean, rstd

    for (int t = tid; t < IC * 3 * 3 * CPG; t += 256) {
        int ch = t & 3;
        int r = t >> 2;                        // ic*9 + kh*3 + kw
        wlds[t] = conv_w[(g * CPG + ch) * (IC * 9) + r];
    }
    float bias[CPG], sgnf[CPG];
#pragma unroll
    for (int ch = 0; ch < CPG; ch++) {
        int c = g * CPG + ch;
        bias[ch] = conv_b[c];
        sgnf[ch] = (gn_w[c] * scale[c] >= 0.f) ? 1.f : -1.f;
    }
    __syncthreads();

    const float* xb = x + (size_t)n * (IC * IH * IW);

    float s = 0.f, ss = 0.f;
    float pm[4][CPG];                // running extreme per owned pool cell
#pragma unroll
    for (int ci = 0; ci < 4; ci++)
#pragma unroll
        for (int ch = 0; ch < CPG; ch++) pm[ci][ch] = -INFINITY;

    // ---- Main: pool region (conv rows/cols 0..123), one pass ----
#pragma unroll
    for (int ci = 0; ci < 4; ci++) {
        int cell = tid + ci * 256;
        if (cell < PH * PW) {
            int ph = cell / PW;
            int pw = cell - ph * PW;
#pragma unroll 1
            for (int r = 0; r < 4; r++) {
                float acc[4][CPG];
#pragma unroll
                for (int j = 0; j < 4; j++)
#pragma unroll
                    for (int ch = 0; ch < CPG; ch++) acc[j][ch] = bias[ch];

                conv4(xb, wlds, 4 * ph + r, 4 * pw, false, acc);

#pragma unroll
                for (int j = 0; j < 4; j++)
#pragma unroll
                    for (int ch = 0; ch < CPG; ch++) {
                        float v = acc[j][ch];
                        s += v;
                        ss = fmaf(v, v, ss);
                        pm[ci][ch] = fmaxf(pm[ci][ch], v * sgnf[ch]);
                    }
            }
        }
    }

    // ---- Edges: conv outputs needed for stats only ----
    if (tid < 124) {
        // right edge: oh=tid, cols 124..125
        float acc[4][CPG];
#pragma unroll
        for (int j = 0; j < 4; j++)
#pragma unroll
            for (int ch = 0; ch < CPG; ch++) acc[j][ch] = bias[ch];
        conv4(xb, wlds, tid, 124, true, acc);
#pragma unroll
        for (int j = 0; j < 2; j++)
#pragma unroll
            for (int ch = 0; ch < CPG; ch++) {
                float v = acc[j][ch];
                s += v;
                ss = fmaf(v, v, ss);
            }
    } else if (tid >= 128 && tid < 192) {
        // bottom rows: oh in {124,125}, all 126 cols
        int idx = tid - 128;
        int oh = 124 + (idx >> 5);
        int q = idx & 31;
        bool edge = (q == 31);
        float acc[4][CPG];
#pragma unroll
        for (int j = 0; j < 4; j++)
#pragma unroll
            for (int ch = 0; ch < CPG; ch++) acc[j][ch] = bias[ch];
        conv4(xb, wlds, oh, q * 4, edge, acc);
        int jmax = edge ? 2 : 4;
#pragma unroll
        for (int j = 0; j < 4; j++) {
            if (j < jmax) {
#pragma unroll
                for (int ch = 0; ch < CPG; ch++) {
                    float v = acc[j][ch];
                    s += v;
                    ss = fmaf(v, v, ss);
                }
            }
        }
    }

    // ---- Block reduction for GN stats ----
#pragma unroll
    for (int off = 32; off > 0; off >>= 1) {
        s  += __shfl_down(s, off, 64);
        ss += __shfl_down(ss, off, 64);
    }
    int wave = tid >> 6;
    if ((tid & 63) == 0) { red[wave] = s; red[4 + wave] = ss; }
    __syncthreads();
    if (tid == 0) {
        float S  = red[0] + red[1] + red[2] + red[3];
        float SS = red[4] + red[5] + red[6] + red[7];
        const float inv_count = 1.f / (float)(CPG * OH * OW);
        float mean = S * inv_count;
        float var = SS * inv_count - mean * mean;
        if (var < 0.f) var = 0.f;
        stats[0] = mean;
        stats[1] = rsqrtf(var + GN_EPS);
    }
    __syncthreads();
    const float mean = stats[0];
    const float rstd = stats[1];

    // Fused affine for the pooled extreme: out = a2*M + b2  (a2 >= 0)
    float a2[CPG], b2[CPG];
#pragma unroll
    for (int ch = 0; ch < CPG; ch++) {
        int c = g * CPG + ch;
        float gw = gn_w[c], sc = scale[c];
        a2[ch] = rstd * fabsf(gw * sc);
        b2[ch] = (gn_b[c] - mean * rstd * gw) * sc;
    }

    // ---- Write pooled, clamped output ----
#pragma unroll
    for (int ci = 0; ci < 4; ci++) {
        int cell = tid + ci * 256;
        if (cell < PH * PW) {
            int ph = cell / PW;
            int pw = cell - ph * PW;
#pragma unroll
            for (int ch = 0; ch < CPG; ch++) {
                int c = g * CPG + ch;
                float v = fmaf(a2[ch], pm[ci][ch], b2[ch]);
                v = fminf(fmaxf(v, 0.f), 1.f);
                out[(((size_t)n * OC + c) * PH + ph) * PW + pw] = v;
            }
        }
    }
}

extern "C" void kernel_launch(void* const* d_in, const int* in_sizes, int n_in,
                              void* d_out, int out_size, void* d_ws, size_t ws_size,
                              hipStream_t stream) {
    const float* x      = (const float*)d_in[0];
    const float* conv_w = (const float*)d_in[1];
    const float* conv_b = (const float*)d_in[2];
    const float* gn_w   = (const float*)d_in[3];
    const float* gn_b   = (const float*)d_in[4];
    const float* scale  = (const float*)d_in[5];
    float* out = (float*)d_out;

    dim3 grid(N_IMG * NG);   // one block per (n, group)
    dim3 block(256);
    hipLaunchKernelGGL(fused_conv_gn_pool_kernel, grid, block, 0, stream,
                       x, conv_w, conv_b, gn_w, gn_b, scale, out);
}